// Round 3
// baseline (865.133 us; speedup 1.0000x reference)
//
#include <hip/hip_runtime.h>
#include <cstddef>

#define NN 256
#define LL 2048
#define BB 128
#define CC 16
#define MM 128   // LL/CC

// workspace layout (float offsets)
#define Q_OFF 0                      // CC matrices of NN*NN: Q_j = (dA^{j+1})^T
#define K_OFF (CC * NN * NN)         // CC vectors of NN:    K_r = dA^r dB
#define E_OFF (K_OFF + CC * NN)      // MM*BB*NN: chunk-end locals, then overwritten by S_m

// ---------------- Q_0 = dA^T ----------------
__global__ void k_transpose(const float* __restrict__ dA, float* __restrict__ ws) {
    int idx = blockIdx.x * 256 + threadIdx.x;   // 0..65535
    int a = idx >> 8, i = idx & 255;
    ws[Q_OFF + a * NN + i] = dA[i * NN + a];
}

// ---------------- power doubling in Q-space: Q_{a-1} = Q_{a-baseB-1} @ Q_{baseB-1} ----------------
__global__ void k_qmm(float* __restrict__ ws, int baseB) {
    int matIdx = blockIdx.x >> 8;        // 0..count-1
    int u = blockIdx.x & 255;            // output row
    int a = baseB + 1 + matIdx;          // power being formed
    const float* lhs = ws + Q_OFF + (size_t)(a - baseB - 1) * NN * NN;
    const float* rhs = ws + Q_OFF + (size_t)(baseB - 1) * NN * NN;
    float* dst = ws + Q_OFF + (size_t)(a - 1) * NN * NN;
    __shared__ float row[NN];
    row[threadIdx.x] = lhs[u * NN + threadIdx.x];
    __syncthreads();
    int v = threadIdx.x;
    float acc = 0.f;
    #pragma unroll 8
    for (int w = 0; w < NN; ++w) acc += row[w] * rhs[w * NN + v];
    dst[u * NN + v] = acc;
}

// ---------------- K_r = dA^r dB ----------------
__global__ void k_kvec(const float* __restrict__ dB, float* __restrict__ ws) {
    int r = blockIdx.x, i = threadIdx.x;
    float acc;
    if (r == 0) {
        acc = dB[i];
    } else {
        const float* Qr = ws + Q_OFF + (size_t)(r - 1) * NN * NN;
        acc = 0.f;
        #pragma unroll 8
        for (int a = 0; a < NN; ++a) acc += Qr[a * NN + i] * dB[a];
    }
    ws[K_OFF + r * NN + i] = acc;
}

// ---------------- phase 1: E_m[b,i] = sum_k in[mC+k,b] * K_{C-1-k}[i] ----------------
__global__ void k_phase1(const float* __restrict__ in, float* __restrict__ ws) {
    int m = blockIdx.x >> 2;
    int bs = (blockIdx.x & 3) * 32;
    __shared__ float in_s[CC][32];
    __shared__ float K_s[CC][NN];
    int tid = threadIdx.x;
    for (int x = tid; x < CC * 32; x += 256) {
        int k = x >> 5, b = x & 31;
        in_s[k][b] = in[(m * CC + k) * BB + bs + b];
    }
    for (int x = tid; x < CC * NN; x += 256) {
        K_s[x >> 8][x & 255] = ws[K_OFF + x];
    }
    __syncthreads();
    int i = tid;
    float acc[32];
    #pragma unroll
    for (int b = 0; b < 32; ++b) acc[b] = 0.f;
    #pragma unroll
    for (int k = 0; k < CC; ++k) {
        float kv = K_s[CC - 1 - k][i];
        #pragma unroll
        for (int b = 0; b < 32; ++b) acc[b] += in_s[k][b] * kv;
    }
    #pragma unroll
    for (int b = 0; b < 32; ++b)
        ws[E_OFF + (size_t)(m * BB + bs + b) * NN + i] = acc[b];
}

// ---------------- phase 2: boundary scan, one block per batch b ----------------
// s_{m+1} = s_m @ Q_{C-1} + E_m ; writes S_m (state at START of chunk m) over slot m.
__global__ void __launch_bounds__(1024) k_phase2(float* __restrict__ ws) {
    int b = blockIdx.x;
    int tid = threadIdx.x;
    int i = tid & 255, q = tid >> 8;     // q = 0..3 (a-range owner)
    const float* Qc = ws + Q_OFF + (size_t)(CC - 1) * NN * NN;  // (dA^C)^T
    float qreg[64];
    #pragma unroll
    for (int w = 0; w < 64; ++w) qreg[w] = Qc[(q * 64 + w) * NN + i];
    __shared__ float s_lds[NN];
    __shared__ float part[1024];
    if (tid < NN) s_lds[tid] = 0.f;
    __syncthreads();
    float* EA = ws + E_OFF;
    for (int m = 0; m < MM; ++m) {
        float e = 0.f, scur = 0.f;
        if (tid < NN) {
            e = EA[(size_t)(m * BB + b) * NN + tid];   // E[m,b,i]
            scur = s_lds[tid];                          // S_m[b,i]
        }
        float acc = 0.f;
        const float4* s4 = (const float4*)(s_lds + q * 64);
        #pragma unroll
        for (int w4 = 0; w4 < 16; ++w4) {
            float4 sv = s4[w4];
            acc += sv.x * qreg[w4 * 4 + 0] + sv.y * qreg[w4 * 4 + 1] +
                   sv.z * qreg[w4 * 4 + 2] + sv.w * qreg[w4 * 4 + 3];
        }
        part[tid] = acc;
        __syncthreads();
        if (tid < NN) {
            float sn = part[tid] + part[256 + tid] + part[512 + tid] + part[768 + tid] + e;
            EA[(size_t)(m * BB + b) * NN + tid] = scur;  // slot m now holds S_m
            s_lds[tid] = sn;
        }
        __syncthreads();
    }
}

// ---------------- phase 3: out[mC+j] = S_m @ Q_j + local rank-1 conv ----------------
__global__ void __launch_bounds__(256) k_phase3(const float* __restrict__ in,
                                                float* __restrict__ out,
                                                const float* __restrict__ ws) {
    int bid = blockIdx.x;            // MM*CC*4 blocks
    int bs = (bid & 3) * 32;
    int j  = (bid >> 2) & 15;
    int m  = bid >> 6;
    const float* Qj = ws + Q_OFF + (size_t)j * NN * NN;
    const float* SA = ws + E_OFF + (size_t)(m * BB) * NN;
    const float* Kv = ws + K_OFF;
    __shared__ float S_s[32][NN];
    __shared__ float in_s[CC][32];
    int tid = threadIdx.x;
    for (int x = tid; x < 32 * NN; x += 256) {
        S_s[x >> 8][x & 255] = SA[(size_t)(bs + (x >> 8)) * NN + (x & 255)];
    }
    for (int x = tid; x < CC * 32; x += 256) {
        int k = x >> 5, b2 = x & 31;
        in_s[k][b2] = in[(m * CC + k) * BB + bs + b2];
    }
    __syncthreads();
    int i0 = tid & 63, bq = tid >> 6;   // bq 0..3 -> 8 b's each
    float acc[8][4];
    #pragma unroll
    for (int bb = 0; bb < 8; ++bb)
        #pragma unroll
        for (int ii = 0; ii < 4; ++ii) acc[bb][ii] = 0.f;

    // main correction: sum_a S[b,a] * Qj[a,i]
    for (int a4 = 0; a4 < 64; ++a4) {
        float sv[8][4];
        #pragma unroll
        for (int bb = 0; bb < 8; ++bb)
            *(float4*)sv[bb] = *(const float4*)(&S_s[bq * 8 + bb][a4 * 4]);
        #pragma unroll
        for (int aa = 0; aa < 4; ++aa) {
            int a = a4 * 4 + aa;
            float q0 = Qj[a * NN + i0];
            float q1 = Qj[a * NN + 64 + i0];
            float q2 = Qj[a * NN + 128 + i0];
            float q3 = Qj[a * NN + 192 + i0];
            #pragma unroll
            for (int bb = 0; bb < 8; ++bb) {
                float s = sv[bb][aa];
                acc[bb][0] += s * q0;
                acc[bb][1] += s * q1;
                acc[bb][2] += s * q2;
                acc[bb][3] += s * q3;
            }
        }
    }
    // local conv: sum_{k<=j} in[mC+k,b] * K_{j-k}[i]
    for (int k = 0; k <= j; ++k) {
        const float* Kr = Kv + (j - k) * NN;
        float k0 = Kr[i0], k1 = Kr[64 + i0], k2 = Kr[128 + i0], k3 = Kr[192 + i0];
        #pragma unroll
        for (int bb = 0; bb < 8; ++bb) {
            float uin = in_s[k][bq * 8 + bb];
            acc[bb][0] += uin * k0;
            acc[bb][1] += uin * k1;
            acc[bb][2] += uin * k2;
            acc[bb][3] += uin * k3;
        }
    }
    int t = m * CC + j;
    float* op = out + (size_t)t * BB * NN;
    #pragma unroll
    for (int bb = 0; bb < 8; ++bb) {
        int b = bs + bq * 8 + bb;
        #pragma unroll
        for (int ii = 0; ii < 4; ++ii)
            op[(size_t)b * NN + ii * 64 + i0] = acc[bb][ii];
    }
}

extern "C" void kernel_launch(void* const* d_in, const int* in_sizes, int n_in,
                              void* d_out, int out_size, void* d_ws, size_t ws_size,
                              hipStream_t stream) {
    const float* in = (const float*)d_in[0];   // (L, B)
    const float* dA = (const float*)d_in[1];   // (N, N)
    const float* dB = (const float*)d_in[2];   // (N,)
    float* out = (float*)d_out;                // (L, B, N)
    float* ws  = (float*)d_ws;                 // needs ~21 MB

    k_transpose<<<256, 256, 0, stream>>>(dA, ws);
    k_qmm<<<1 * 256, 256, 0, stream>>>(ws, 1);   // Q_1
    k_qmm<<<2 * 256, 256, 0, stream>>>(ws, 2);   // Q_2, Q_3
    k_qmm<<<4 * 256, 256, 0, stream>>>(ws, 4);   // Q_4..Q_7
    k_qmm<<<8 * 256, 256, 0, stream>>>(ws, 8);   // Q_8..Q_15
    k_kvec<<<CC, 256, 0, stream>>>(dB, ws);
    k_phase1<<<MM * 4, 256, 0, stream>>>(in, ws);
    k_phase2<<<BB, 1024, 0, stream>>>(ws);
    k_phase3<<<MM * CC * 4, 256, 0, stream>>>(in, out, ws);
}

// Round 4
// 718.788 us; speedup vs baseline: 1.2036x; 1.2036x over previous
//
#include <hip/hip_runtime.h>
#include <cstddef>

#define NN 256
#define LL 2048
#define BB 128
#define CC 16
#define MM 128   // LL/CC

// ---- f32 workspace layout (float offsets) ----
#define Q_OFF 0                      // CC matrices of NN*NN: Q_j = (dA^{j+1})^T
#define K_OFF (CC * NN * NN)         // CC vectors of NN:    K_r = dA^r dB
#define E_OFF (K_OFF + CC * NN)      // MM*BB*NN: E_m, then S_m after phase2
#define F32_FLOATS (E_OFF + MM * BB * NN)   // 5,246,976 floats

// ---- bf16 fragment buffers (ushort elems, after f32 region) ----
// Qb: [j][kt*16+ct][lane][8]  (16 * 9*16*512 = 1,179,648 each of hi/lo)
// Sb: [m][kt*8+rt][lane][8]   (128 * 9*8*512 = 4,718,592 each of hi/lo)
#define QB_ELEMS (CC * 9 * 16 * 512)
#define SB_ELEMS (MM * 9 * 8 * 512)
#define NEED_BYTES ((size_t)F32_FLOATS * 4 + ((size_t)QB_ELEMS * 2 + (size_t)SB_ELEMS * 2) * 2)

typedef __attribute__((ext_vector_type(8))) short short8;
typedef __attribute__((ext_vector_type(4))) float f32x4;

__device__ inline unsigned short f2bf_rn(float x) {
    unsigned int u = __float_as_uint(x);
    unsigned int r = (u + 0x7FFFu + ((u >> 16) & 1u)) >> 16;
    return (unsigned short)r;
}
__device__ inline float bf2f(unsigned short h) {
    return __uint_as_float(((unsigned int)h) << 16);
}
__device__ inline void bf16split(float v, unsigned short& h, unsigned short& l) {
    h = f2bf_rn(v);
    l = f2bf_rn(v - bf2f(h));
}

// ---------------- Q_0 = dA^T ----------------
__global__ void k_transpose(const float* __restrict__ dA, float* __restrict__ ws) {
    int idx = blockIdx.x * 256 + threadIdx.x;
    int a = idx >> 8, i = idx & 255;
    ws[Q_OFF + a * NN + i] = dA[i * NN + a];
}

// ---------------- power doubling: Q_{a-1} = Q_{a-baseB-1} @ Q_{baseB-1} ----------------
__global__ void k_qmm(float* __restrict__ ws, int baseB) {
    int matIdx = blockIdx.x >> 8;
    int u = blockIdx.x & 255;
    int a = baseB + 1 + matIdx;
    const float* lhs = ws + Q_OFF + (size_t)(a - baseB - 1) * NN * NN;
    const float* rhs = ws + Q_OFF + (size_t)(baseB - 1) * NN * NN;
    float* dst = ws + Q_OFF + (size_t)(a - 1) * NN * NN;
    __shared__ float row[NN];
    row[threadIdx.x] = lhs[u * NN + threadIdx.x];
    __syncthreads();
    int v = threadIdx.x;
    float acc = 0.f;
    #pragma unroll 8
    for (int w = 0; w < NN; ++w) acc += row[w] * rhs[w * NN + v];
    dst[u * NN + v] = acc;
}

// ---------------- K_r = dA^r dB ----------------
__global__ void k_kvec(const float* __restrict__ dB, float* __restrict__ ws) {
    int r = blockIdx.x, i = threadIdx.x;
    float acc;
    if (r == 0) {
        acc = dB[i];
    } else {
        const float* Qr = ws + Q_OFF + (size_t)(r - 1) * NN * NN;
        acc = 0.f;
        #pragma unroll 8
        for (int a = 0; a < NN; ++a) acc += Qr[a * NN + i] * dB[a];
    }
    ws[K_OFF + r * NN + i] = acc;
}

// ---------------- phase 1: E_m[b,i] = sum_k in[mC+k,b] * K_{C-1-k}[i] ----------------
__global__ void k_phase1(const float* __restrict__ in, float* __restrict__ ws) {
    int m = blockIdx.x >> 2;
    int bs = (blockIdx.x & 3) * 32;
    __shared__ float in_s[CC][32];
    __shared__ float K_s[CC][NN];
    int tid = threadIdx.x;
    for (int x = tid; x < CC * 32; x += 256) {
        int k = x >> 5, b = x & 31;
        in_s[k][b] = in[(m * CC + k) * BB + bs + b];
    }
    for (int x = tid; x < CC * NN; x += 256) {
        K_s[x >> 8][x & 255] = ws[K_OFF + x];
    }
    __syncthreads();
    int i = tid;
    float acc[32];
    #pragma unroll
    for (int b = 0; b < 32; ++b) acc[b] = 0.f;
    #pragma unroll
    for (int k = 0; k < CC; ++k) {
        float kv = K_s[CC - 1 - k][i];
        #pragma unroll
        for (int b = 0; b < 32; ++b) acc[b] += in_s[k][b] * kv;
    }
    #pragma unroll
    for (int b = 0; b < 32; ++b)
        ws[E_OFF + (size_t)(m * BB + bs + b) * NN + i] = acc[b];
}

// ---------------- phase 2: boundary scan with E-prefetch ----------------
__global__ void __launch_bounds__(1024) k_phase2(float* __restrict__ ws) {
    int b = blockIdx.x;
    int tid = threadIdx.x;
    int i = tid & 255, q = tid >> 8;
    const float* Qc = ws + Q_OFF + (size_t)(CC - 1) * NN * NN;
    float qreg[64];
    #pragma unroll
    for (int w = 0; w < 64; ++w) qreg[w] = Qc[(q * 64 + w) * NN + i];
    __shared__ float s_lds[NN];
    __shared__ float part[1024];
    if (tid < NN) s_lds[tid] = 0.f;
    float* EA = ws + E_OFF;
    float e_next = 0.f;
    if (tid < NN) e_next = EA[(size_t)b * NN + tid];   // prefetch m=0
    __syncthreads();
    for (int m = 0; m < MM; ++m) {
        float e = e_next, scur = 0.f;
        if (m + 1 < MM && tid < NN)
            e_next = EA[(size_t)((m + 1) * BB + b) * NN + tid];  // prefetch next
        if (tid < NN) scur = s_lds[tid];
        float acc = 0.f;
        const float4* s4 = (const float4*)(s_lds + q * 64);
        #pragma unroll
        for (int w4 = 0; w4 < 16; ++w4) {
            float4 sv = s4[w4];
            acc += sv.x * qreg[w4 * 4 + 0] + sv.y * qreg[w4 * 4 + 1] +
                   sv.z * qreg[w4 * 4 + 2] + sv.w * qreg[w4 * 4 + 3];
        }
        part[tid] = acc;
        __syncthreads();
        if (tid < NN) {
            float sn = part[tid] + part[256 + tid] + part[512 + tid] + part[768 + tid] + e;
            EA[(size_t)(m * BB + b) * NN + tid] = scur;  // slot m now holds S_m
            s_lds[tid] = sn;
        }
        __syncthreads();
    }
}

// ---------------- prep: Q'_j (288x256 augmented, conv folded in) -> bf16 hi/lo fragments ----
__global__ void k_qsplit(const float* __restrict__ ws,
                         unsigned short* __restrict__ qbh, unsigned short* __restrict__ qbl) {
    int g = blockIdx.x * 256 + threadIdx.x;    // 16*9*16*64 = 147456
    int j = g / 9216;
    int rem = g - j * 9216;
    int kt = rem >> 10;
    int rem2 = rem & 1023;
    int ct = rem2 >> 6, lane = rem2 & 63;
    const float* Q = ws + Q_OFF + (size_t)j * NN * NN;
    const float* K = ws + K_OFF;
    int col = ct * 16 + (lane & 15);
    int kbase = kt * 32 + (lane >> 4) * 8;
    size_t o = (size_t)j * (9 * 16 * 512) + (size_t)(kt * 16 + ct) * 512 + lane * 8;
    #pragma unroll
    for (int jj = 0; jj < 8; ++jj) {
        int k = kbase + jj;
        float v;
        if (k < NN) {
            v = Q[(size_t)k * NN + col];
        } else {
            int kk = k - NN;
            v = (kk < CC && kk <= j) ? K[(size_t)(j - kk) * NN + col] : 0.f;
        }
        unsigned short h, l;
        bf16split(v, h, l);
        qbh[o + jj] = h;
        qbl[o + jj] = l;
    }
}

// ---------------- prep: S'_m (128x288 augmented: S_m | in-chunk) -> bf16 hi/lo fragments ----
__global__ void k_ssplit(const float* __restrict__ in, const float* __restrict__ ws,
                         unsigned short* __restrict__ sbh, unsigned short* __restrict__ sbl) {
    int g = blockIdx.x * 256 + threadIdx.x;    // 128*9*8*64 = 589824
    int m = g / 4608;
    int rem = g - m * 4608;
    int kt = rem >> 9;
    int rem2 = rem & 511;
    int rt = rem2 >> 6, lane = rem2 & 63;
    int b = rt * 16 + (lane & 15);
    int kbase = kt * 32 + (lane >> 4) * 8;
    const float* S = ws + E_OFF;
    size_t o = (size_t)m * (9 * 8 * 512) + (size_t)(kt * 8 + rt) * 512 + lane * 8;
    #pragma unroll
    for (int jj = 0; jj < 8; ++jj) {
        int k = kbase + jj;
        float v;
        if (k < NN) {
            v = S[((size_t)m * BB + b) * NN + k];
        } else {
            int kk = k - NN;
            v = (kk < CC) ? in[(size_t)(m * CC + kk) * BB + b] : 0.f;
        }
        unsigned short h, l;
        bf16split(v, h, l);
        sbh[o + jj] = h;
        sbl[o + jj] = l;
    }
}

// ---------------- phase 3 (MFMA): out[mC+j] = S'_m @ Q'_j, 3-term double-bf16 ----------------
__global__ void __launch_bounds__(256) k_phase3_mfma(
    const unsigned short* __restrict__ sbh, const unsigned short* __restrict__ sbl,
    const unsigned short* __restrict__ qbh, const unsigned short* __restrict__ qbl,
    float* __restrict__ out)
{
    int bid = blockIdx.x;
    int j = bid & (CC - 1), m = bid >> 4;
    int tid = threadIdx.x;
    int wave = tid >> 6, lane = tid & 63;

    const unsigned short* sh = sbh + (size_t)m * (9 * 8 * 512);
    const unsigned short* sl = sbl + (size_t)m * (9 * 8 * 512);
    const unsigned short* qh = qbh + (size_t)j * (9 * 16 * 512);
    const unsigned short* ql = qbl + (size_t)j * (9 * 16 * 512);

    f32x4 acc[8][4];
    #pragma unroll
    for (int r = 0; r < 8; ++r)
        #pragma unroll
        for (int c = 0; c < 4; ++c) acc[r][c] = (f32x4){0.f, 0.f, 0.f, 0.f};

    const int laneoff = lane * 8;
    #pragma unroll 1
    for (int pass = 0; pass < 3; ++pass) {
        const unsigned short* sp = (pass == 1) ? sl : sh;   // hh, lh, hl
        const unsigned short* qp = (pass == 2) ? ql : qh;
        #pragma unroll
        for (int kt = 0; kt < 9; ++kt) {
            short8 af[8], bfr[4];
            const unsigned short* ab = sp + (size_t)kt * (8 * 512) + laneoff;
            #pragma unroll
            for (int r = 0; r < 8; ++r)
                af[r] = *(const short8*)(ab + r * 512);
            const unsigned short* bb = qp + (size_t)(kt * 16 + wave * 4) * 512 + laneoff;
            #pragma unroll
            for (int c = 0; c < 4; ++c)
                bfr[c] = *(const short8*)(bb + c * 512);
            #pragma unroll
            for (int r = 0; r < 8; ++r)
                #pragma unroll
                for (int c = 0; c < 4; ++c)
                    acc[r][c] = __builtin_amdgcn_mfma_f32_16x16x32_bf16(af[r], bfr[c], acc[r][c], 0, 0, 0);
        }
    }
    float* op = out + (size_t)(m * CC + j) * (BB * NN);
    int r0 = (lane >> 4) * 4;     // D: row=(lane>>4)*4+reg, col=lane&15  [m89-verified]
    int col = lane & 15;
    #pragma unroll
    for (int rt = 0; rt < 8; ++rt) {
        #pragma unroll
        for (int c = 0; c < 4; ++c) {
            int i = wave * 64 + c * 16 + col;
            #pragma unroll
            for (int rr = 0; rr < 4; ++rr) {
                int b = rt * 16 + r0 + rr;
                op[(size_t)b * NN + i] = acc[rt][c][rr];
            }
        }
    }
}

// ---------------- phase 3 fallback (f32 vector, known-passing) ----------------
__global__ void __launch_bounds__(256) k_phase3(const float* __restrict__ in,
                                                float* __restrict__ out,
                                                const float* __restrict__ ws) {
    int bid = blockIdx.x;
    int bs = (bid & 3) * 32;
    int j  = (bid >> 2) & 15;
    int m  = bid >> 6;
    const float* Qj = ws + Q_OFF + (size_t)j * NN * NN;
    const float* SA = ws + E_OFF + (size_t)(m * BB) * NN;
    const float* Kv = ws + K_OFF;
    __shared__ float S_s[32][NN];
    __shared__ float in_s[CC][32];
    int tid = threadIdx.x;
    for (int x = tid; x < 32 * NN; x += 256)
        S_s[x >> 8][x & 255] = SA[(size_t)(bs + (x >> 8)) * NN + (x & 255)];
    for (int x = tid; x < CC * 32; x += 256) {
        int k = x >> 5, b2 = x & 31;
        in_s[k][b2] = in[(m * CC + k) * BB + bs + b2];
    }
    __syncthreads();
    int i0 = tid & 63, bq = tid >> 6;
    float acc[8][4];
    #pragma unroll
    for (int bb = 0; bb < 8; ++bb)
        #pragma unroll
        for (int ii = 0; ii < 4; ++ii) acc[bb][ii] = 0.f;
    for (int a4 = 0; a4 < 64; ++a4) {
        float sv[8][4];
        #pragma unroll
        for (int bb = 0; bb < 8; ++bb)
            *(float4*)sv[bb] = *(const float4*)(&S_s[bq * 8 + bb][a4 * 4]);
        #pragma unroll
        for (int aa = 0; aa < 4; ++aa) {
            int a = a4 * 4 + aa;
            float q0 = Qj[a * NN + i0];
            float q1 = Qj[a * NN + 64 + i0];
            float q2 = Qj[a * NN + 128 + i0];
            float q3 = Qj[a * NN + 192 + i0];
            #pragma unroll
            for (int bb = 0; bb < 8; ++bb) {
                float s = sv[bb][aa];
                acc[bb][0] += s * q0; acc[bb][1] += s * q1;
                acc[bb][2] += s * q2; acc[bb][3] += s * q3;
            }
        }
    }
    for (int k = 0; k <= j; ++k) {
        const float* Kr = Kv + (j - k) * NN;
        float k0 = Kr[i0], k1 = Kr[64 + i0], k2 = Kr[128 + i0], k3 = Kr[192 + i0];
        #pragma unroll
        for (int bb = 0; bb < 8; ++bb) {
            float uin = in_s[k][bq * 8 + bb];
            acc[bb][0] += uin * k0; acc[bb][1] += uin * k1;
            acc[bb][2] += uin * k2; acc[bb][3] += uin * k3;
        }
    }
    int t = m * CC + j;
    float* op = out + (size_t)t * BB * NN;
    #pragma unroll
    for (int bb = 0; bb < 8; ++bb) {
        int b = bs + bq * 8 + bb;
        #pragma unroll
        for (int ii = 0; ii < 4; ++ii)
            op[(size_t)b * NN + ii * 64 + i0] = acc[bb][ii];
    }
}

extern "C" void kernel_launch(void* const* d_in, const int* in_sizes, int n_in,
                              void* d_out, int out_size, void* d_ws, size_t ws_size,
                              hipStream_t stream) {
    const float* in = (const float*)d_in[0];   // (L, B)
    const float* dA = (const float*)d_in[1];   // (N, N)
    const float* dB = (const float*)d_in[2];   // (N,)
    float* out = (float*)d_out;                // (L, B, N)
    float* ws  = (float*)d_ws;

    bool mfma_ok = ws_size >= NEED_BYTES;      // ~44.6 MB

    k_transpose<<<256, 256, 0, stream>>>(dA, ws);
    k_qmm<<<1 * 256, 256, 0, stream>>>(ws, 1);
    k_qmm<<<2 * 256, 256, 0, stream>>>(ws, 2);
    k_qmm<<<4 * 256, 256, 0, stream>>>(ws, 4);
    k_qmm<<<8 * 256, 256, 0, stream>>>(ws, 8);
    k_kvec<<<CC, 256, 0, stream>>>(dB, ws);

    unsigned short* qbh = (unsigned short*)(ws + F32_FLOATS);
    unsigned short* qbl = qbh + QB_ELEMS;
    unsigned short* sbh = qbl + QB_ELEMS;
    unsigned short* sbl = sbh + SB_ELEMS;

    if (mfma_ok)
        k_qsplit<<<576, 256, 0, stream>>>(ws, qbh, qbl);

    k_phase1<<<MM * 4, 256, 0, stream>>>(in, ws);
    k_phase2<<<BB, 1024, 0, stream>>>(ws);

    if (mfma_ok) {
        k_ssplit<<<2304, 256, 0, stream>>>(in, ws, sbh, sbl);
        k_phase3_mfma<<<MM * CC, 256, 0, stream>>>(sbh, sbl, qbh, qbl, out);
    } else {
        k_phase3<<<MM * CC * 4, 256, 0, stream>>>(in, out, ws);
    }
}

// Round 5
// 550.346 us; speedup vs baseline: 1.5720x; 1.3061x over previous
//
#include <hip/hip_runtime.h>
#include <cstddef>

#define NN 256
#define LL 2048
#define BB 128
#define CC 32
#define MM 64    // LL/CC
#define KT 9     // K' = NN + CC = 288 = KT*32

// ---- f32 workspace layout (float offsets) ----
#define Q_OFF 0                      // CC matrices of NN*NN: Q_j = (dA^{j+1})^T
#define K_OFF (CC * NN * NN)         // CC vectors of NN:    K_r = dA^r dB
#define E_OFF (K_OFF + CC * NN)      // MM*BB*NN: E_m, then S_m after phase2
#define F32_FLOATS (E_OFF + MM * BB * NN)

// ---- bf16 fragment buffers (ushort elems, after f32 region) ----
// Qb: [j][(kt*16+ct)*512 + lane*8 + e]   per j: KT*16*512 = 73728
// Sb: [m][(kt*8+rt)*512 + lane*8 + e]    per m: KT*8*512  = 36864
#define QB_PER_J (KT * 16 * 512)
#define SB_PER_M (KT * 8 * 512)
#define QB_ELEMS (CC * QB_PER_J)
#define SB_ELEMS (MM * SB_PER_M)
#define NEED_BYTES ((size_t)F32_FLOATS * 4 + ((size_t)QB_ELEMS * 2 + (size_t)SB_ELEMS * 2) * 2)

typedef __attribute__((ext_vector_type(8))) short short8;
typedef __attribute__((ext_vector_type(4))) float f32x4;

__device__ inline unsigned short f2bf_rn(float x) {
    unsigned int u = __float_as_uint(x);
    unsigned int r = (u + 0x7FFFu + ((u >> 16) & 1u)) >> 16;
    return (unsigned short)r;
}
__device__ inline float bf2f(unsigned short h) {
    return __uint_as_float(((unsigned int)h) << 16);
}
__device__ inline void bf16split(float v, unsigned short& h, unsigned short& l) {
    h = f2bf_rn(v);
    l = f2bf_rn(v - bf2f(h));
}

__device__ inline void gl_lds16(const unsigned short* g, unsigned short* l) {
    __builtin_amdgcn_global_load_lds(
        (const __attribute__((address_space(1))) unsigned int*)g,
        (__attribute__((address_space(3))) unsigned int*)l, 16, 0, 0);
}

// ---------------- Q_0 = dA^T ----------------
__global__ void k_transpose(const float* __restrict__ dA, float* __restrict__ ws) {
    int idx = blockIdx.x * 256 + threadIdx.x;
    int a = idx >> 8, i = idx & 255;
    ws[Q_OFF + a * NN + i] = dA[i * NN + a];
}

// ---------------- power doubling, 8-row register-blocked ----------------
// grid: count*32 blocks; builds powers a = baseB+1 .. baseB+count
__global__ void k_qmm(float* __restrict__ ws, int baseB) {
    int matIdx = blockIdx.x >> 5;
    int u0 = (blockIdx.x & 31) << 3;
    int a = baseB + 1 + matIdx;
    const float* lhs = ws + Q_OFF + (size_t)(a - baseB - 1) * NN * NN;
    const float* rhs = ws + Q_OFF + (size_t)(baseB - 1) * NN * NN;
    float* dst = ws + Q_OFF + (size_t)(a - 1) * NN * NN;
    __shared__ float rowS[8][NN];
    int tid = threadIdx.x;
    for (int x = tid; x < 8 * NN; x += 256)
        rowS[x >> 8][x & 255] = lhs[(size_t)(u0 + (x >> 8)) * NN + (x & 255)];
    __syncthreads();
    int v = tid;
    float acc[8];
    #pragma unroll
    for (int r = 0; r < 8; ++r) acc[r] = 0.f;
    #pragma unroll 4
    for (int w = 0; w < NN; ++w) {
        float rv = rhs[(size_t)w * NN + v];
        #pragma unroll
        for (int r = 0; r < 8; ++r) acc[r] += rowS[r][w] * rv;
    }
    #pragma unroll
    for (int r = 0; r < 8; ++r) dst[(size_t)(u0 + r) * NN + v] = acc[r];
}

// ---------------- K_r = dA^r dB ----------------
__global__ void k_kvec(const float* __restrict__ dB, float* __restrict__ ws) {
    int r = blockIdx.x, i = threadIdx.x;
    float acc;
    if (r == 0) {
        acc = dB[i];
    } else {
        const float* Qr = ws + Q_OFF + (size_t)(r - 1) * NN * NN;
        acc = 0.f;
        #pragma unroll 8
        for (int a = 0; a < NN; ++a) acc += Qr[(size_t)a * NN + i] * dB[a];
    }
    ws[K_OFF + r * NN + i] = acc;
}

// ---------------- phase 1: E_m[b,i] = sum_k in[mC+k,b] * K_{C-1-k}[i] ----------------
__global__ void k_phase1(const float* __restrict__ in, float* __restrict__ ws) {
    int m = blockIdx.x >> 2;
    int bs = (blockIdx.x & 3) * 32;
    __shared__ float in_s[CC][32];
    __shared__ float K_s[CC][NN];
    int tid = threadIdx.x;
    for (int x = tid; x < CC * 32; x += 256) {
        int k = x >> 5, b = x & 31;
        in_s[k][b] = in[(size_t)(m * CC + k) * BB + bs + b];
    }
    for (int x = tid; x < CC * NN; x += 256)
        K_s[x >> 8][x & 255] = ws[K_OFF + x];
    __syncthreads();
    int i = tid;
    float acc[32];
    #pragma unroll
    for (int b = 0; b < 32; ++b) acc[b] = 0.f;
    #pragma unroll
    for (int k = 0; k < CC; ++k) {
        float kv = K_s[CC - 1 - k][i];
        #pragma unroll
        for (int b = 0; b < 32; ++b) acc[b] += in_s[k][b] * kv;
    }
    #pragma unroll
    for (int b = 0; b < 32; ++b)
        ws[E_OFF + (size_t)(m * BB + bs + b) * NN + i] = acc[b];
}

// ---------------- phase 2: boundary scan (MM=64 steps) with E-prefetch ----------------
__global__ void __launch_bounds__(1024) k_phase2(float* __restrict__ ws) {
    int b = blockIdx.x;
    int tid = threadIdx.x;
    int i = tid & 255, q = tid >> 8;
    const float* Qc = ws + Q_OFF + (size_t)(CC - 1) * NN * NN;   // (dA^CC)^T
    float qreg[64];
    #pragma unroll
    for (int w = 0; w < 64; ++w) qreg[w] = Qc[(size_t)(q * 64 + w) * NN + i];
    __shared__ float s_lds[NN];
    __shared__ float part[1024];
    if (tid < NN) s_lds[tid] = 0.f;
    float* EA = ws + E_OFF;
    float e_next = 0.f;
    if (tid < NN) e_next = EA[(size_t)b * NN + tid];
    __syncthreads();
    for (int m = 0; m < MM; ++m) {
        float e = e_next, scur = 0.f;
        if (m + 1 < MM && tid < NN)
            e_next = EA[(size_t)((m + 1) * BB + b) * NN + tid];
        if (tid < NN) scur = s_lds[tid];
        float acc = 0.f;
        const float4* s4 = (const float4*)(s_lds + q * 64);
        #pragma unroll
        for (int w4 = 0; w4 < 16; ++w4) {
            float4 sv = s4[w4];
            acc += sv.x * qreg[w4 * 4 + 0] + sv.y * qreg[w4 * 4 + 1] +
                   sv.z * qreg[w4 * 4 + 2] + sv.w * qreg[w4 * 4 + 3];
        }
        part[tid] = acc;
        __syncthreads();
        if (tid < NN) {
            float sn = part[tid] + part[256 + tid] + part[512 + tid] + part[768 + tid] + e;
            EA[(size_t)(m * BB + b) * NN + tid] = scur;   // slot m := S_m
            s_lds[tid] = sn;
        }
        __syncthreads();
    }
}

// ---------------- prep: Q'_j (288x256, conv Toeplitz folded) -> bf16 hi/lo fragments ----
__global__ void k_qsplit(const float* __restrict__ ws,
                         unsigned short* __restrict__ qbh, unsigned short* __restrict__ qbl) {
    int g = blockIdx.x * 256 + threadIdx.x;      // CC*KT*16*64 = 294912
    int j = g / (KT * 16 * 64);
    int rem = g - j * (KT * 16 * 64);
    int kt = rem >> 10;
    int ct = (rem >> 6) & 15;
    int lane = rem & 63;
    const float* Q = ws + Q_OFF + (size_t)j * NN * NN;
    const float* K = ws + K_OFF;
    int col = ct * 16 + (lane & 15);
    int kbase = kt * 32 + (lane >> 4) * 8;
    size_t o = (size_t)j * QB_PER_J + (size_t)(kt * 16 + ct) * 512 + lane * 8;
    #pragma unroll
    for (int jj = 0; jj < 8; ++jj) {
        int k = kbase + jj;
        float v;
        if (k < NN) {
            v = Q[(size_t)k * NN + col];
        } else {
            int kk = k - NN;
            v = (kk <= j) ? K[(size_t)(j - kk) * NN + col] : 0.f;
        }
        unsigned short h, l;
        bf16split(v, h, l);
        qbh[o + jj] = h;
        qbl[o + jj] = l;
    }
}

// ---------------- prep: S'_m (128x288: S_m | in-chunk) -> bf16 hi/lo fragments ----
__global__ void k_ssplit(const float* __restrict__ in, const float* __restrict__ ws,
                         unsigned short* __restrict__ sbh, unsigned short* __restrict__ sbl) {
    int g = blockIdx.x * 256 + threadIdx.x;      // MM*KT*8*64 = 294912
    int m = g / (KT * 8 * 64);
    int rem = g - m * (KT * 8 * 64);
    int kt = rem >> 9;
    int rt = (rem >> 6) & 7;
    int lane = rem & 63;
    int b = rt * 16 + (lane & 15);
    int kbase = kt * 32 + (lane >> 4) * 8;
    const float* S = ws + E_OFF;
    size_t o = (size_t)m * SB_PER_M + (size_t)(kt * 8 + rt) * 512 + lane * 8;
    #pragma unroll
    for (int jj = 0; jj < 8; ++jj) {
        int k = kbase + jj;
        float v;
        if (k < NN) {
            v = S[((size_t)m * BB + b) * NN + k];
        } else {
            v = in[(size_t)(m * CC + (k - NN)) * BB + b];
        }
        unsigned short h, l;
        bf16split(v, h, l);
        sbh[o + jj] = h;
        sbl[o + jj] = l;
    }
}

// ---------------- phase 3 (MFMA, LDS-pipelined): out[mC+j] half-tile = S'_m @ Q'_j ----
// grid 4096 = (m 64) x (j 32) x (h 2); block 256 thr; XCD-swizzled.
__global__ void __launch_bounds__(256, 4) k_phase3_mfma(
    const unsigned short* __restrict__ sbh, const unsigned short* __restrict__ sbl,
    const unsigned short* __restrict__ qbh, const unsigned short* __restrict__ qbl,
    float* __restrict__ out)
{
    int bid = blockIdx.x;
    int nb = (bid & 7) * 512 + (bid >> 3);   // bijective XCD swizzle (4096 = 8*512)
    int h = nb & 1;
    int j = (nb >> 1) & 31;
    int m = nb >> 6;
    int tid = threadIdx.x;
    int wave = tid >> 6, lane = tid & 63;

    const unsigned short* sh = sbh + (size_t)m * SB_PER_M;
    const unsigned short* sl = sbl + (size_t)m * SB_PER_M;
    const unsigned short* qh = qbh + (size_t)j * QB_PER_J;
    const unsigned short* ql = qbl + (size_t)j * QB_PER_J;

    __shared__ unsigned short Ab[2][8 * 512];    // 8 KB each
    __shared__ unsigned short Bb[2][8 * 512];    // 8 KB each -> 32 KB total

    f32x4 acc[8][2];
    #pragma unroll
    for (int r = 0; r < 8; ++r)
        #pragma unroll
        for (int c = 0; c < 2; ++c) acc[r][c] = (f32x4){0.f, 0.f, 0.f, 0.f};

    // stage helper inlined: wave copies chunks wave*2, wave*2+1 of A and B kt-slices
    #define STAGE(buf, sp, qp, ktv)                                                   \
        do {                                                                          \
            const unsigned short* ga = (sp) + (size_t)(ktv) * 4096 +                  \
                                       (wave * 2) * 512 + lane * 8;                   \
            gl_lds16(ga,       &Ab[buf][(wave * 2) * 512]);                           \
            gl_lds16(ga + 512, &Ab[buf][(wave * 2 + 1) * 512]);                       \
            const unsigned short* gb = (qp) + ((size_t)(ktv) * 16 + h * 8 +           \
                                       wave * 2) * 512 + lane * 8;                    \
            gl_lds16(gb,       &Bb[buf][(wave * 2) * 512]);                           \
            gl_lds16(gb + 512, &Bb[buf][(wave * 2 + 1) * 512]);                       \
        } while (0)

    STAGE(0, sh, qh, 0);
    __syncthreads();

    const unsigned short* sp = sh;
    const unsigned short* qp = qh;
    int kt = 0, pass = 0;
    #pragma unroll 1
    for (int s = 0; s < 3 * KT; ++s) {
        int cur = s & 1;
        int ktn = kt + 1, pn = pass;
        const unsigned short* spn = sp;
        const unsigned short* qpn = qp;
        if (ktn == KT) {
            ktn = 0; pn = pass + 1;
            spn = (pn == 1) ? sl : sh;      // pass order: (sh,qh), (sl,qh), (sh,ql)
            qpn = (pn == 2) ? ql : qh;
        }
        if (s < 3 * KT - 1) STAGE(cur ^ 1, spn, qpn, ktn);

        short8 af[8];
        #pragma unroll
        for (int r = 0; r < 8; ++r)
            af[r] = *(const short8*)&Ab[cur][r * 512 + lane * 8];
        #pragma unroll
        for (int c = 0; c < 2; ++c) {
            short8 bf = *(const short8*)&Bb[cur][(wave * 2 + c) * 512 + lane * 8];
            #pragma unroll
            for (int r = 0; r < 8; ++r)
                acc[r][c] = __builtin_amdgcn_mfma_f32_16x16x32_bf16(af[r], bf, acc[r][c], 0, 0, 0);
        }
        __syncthreads();    // drains vmcnt(0): next-buf staged; lgkm done; barrier
        kt = ktn; pass = pn; sp = spn; qp = qpn;
    }
    #undef STAGE

    float* op = out + (size_t)(m * CC + j) * (BB * NN);
    int r0 = (lane >> 4) * 4;    // D: row=(lane>>4)*4+reg, col=lane&15  [m89-verified]
    int col = lane & 15;
    #pragma unroll
    for (int rt = 0; rt < 8; ++rt) {
        #pragma unroll
        for (int c = 0; c < 2; ++c) {
            int i = h * 128 + wave * 32 + c * 16 + col;
            #pragma unroll
            for (int rr = 0; rr < 4; ++rr) {
                int b = rt * 16 + r0 + rr;
                op[(size_t)b * NN + i] = acc[rt][c][rr];
            }
        }
    }
}

// ---------------- phase 3 fallback (f32 vector, known-passing) ----------------
__global__ void __launch_bounds__(256) k_phase3(const float* __restrict__ in,
                                                float* __restrict__ out,
                                                const float* __restrict__ ws) {
    int bid = blockIdx.x;                 // MM*CC*4 blocks
    int bs = (bid & 3) * 32;
    int j  = (bid >> 2) & (CC - 1);
    int m  = bid >> 7;
    const float* Qj = ws + Q_OFF + (size_t)j * NN * NN;
    const float* SA = ws + E_OFF + (size_t)(m * BB) * NN;
    const float* Kv = ws + K_OFF;
    __shared__ float S_s[32][NN];
    __shared__ float in_s[CC][32];
    int tid = threadIdx.x;
    for (int x = tid; x < 32 * NN; x += 256)
        S_s[x >> 8][x & 255] = SA[(size_t)(bs + (x >> 8)) * NN + (x & 255)];
    for (int x = tid; x < CC * 32; x += 256) {
        int k = x >> 5, b2 = x & 31;
        in_s[k][b2] = in[(size_t)(m * CC + k) * BB + bs + b2];
    }
    __syncthreads();
    int i0 = tid & 63, bq = tid >> 6;
    float acc[8][4];
    #pragma unroll
    for (int bb = 0; bb < 8; ++bb)
        #pragma unroll
        for (int ii = 0; ii < 4; ++ii) acc[bb][ii] = 0.f;
    for (int a4 = 0; a4 < 64; ++a4) {
        float sv[8][4];
        #pragma unroll
        for (int bb = 0; bb < 8; ++bb)
            *(float4*)sv[bb] = *(const float4*)(&S_s[bq * 8 + bb][a4 * 4]);
        #pragma unroll
        for (int aa = 0; aa < 4; ++aa) {
            int a = a4 * 4 + aa;
            float q0 = Qj[a * NN + i0];
            float q1 = Qj[a * NN + 64 + i0];
            float q2 = Qj[a * NN + 128 + i0];
            float q3 = Qj[a * NN + 192 + i0];
            #pragma unroll
            for (int bb = 0; bb < 8; ++bb) {
                float s = sv[bb][aa];
                acc[bb][0] += s * q0; acc[bb][1] += s * q1;
                acc[bb][2] += s * q2; acc[bb][3] += s * q3;
            }
        }
    }
    for (int k = 0; k <= j; ++k) {
        const float* Kr = Kv + (size_t)(j - k) * NN;
        float k0 = Kr[i0], k1 = Kr[64 + i0], k2 = Kr[128 + i0], k3 = Kr[192 + i0];
        #pragma unroll
        for (int bb = 0; bb < 8; ++bb) {
            float uin = in_s[k][bq * 8 + bb];
            acc[bb][0] += uin * k0; acc[bb][1] += uin * k1;
            acc[bb][2] += uin * k2; acc[bb][3] += uin * k3;
        }
    }
    float* op = out + (size_t)(m * CC + j) * (BB * NN);
    #pragma unroll
    for (int bb = 0; bb < 8; ++bb) {
        int b = bs + bq * 8 + bb;
        #pragma unroll
        for (int ii = 0; ii < 4; ++ii)
            op[(size_t)b * NN + ii * 64 + i0] = acc[bb][ii];
    }
}

extern "C" void kernel_launch(void* const* d_in, const int* in_sizes, int n_in,
                              void* d_out, int out_size, void* d_ws, size_t ws_size,
                              hipStream_t stream) {
    const float* in = (const float*)d_in[0];   // (L, B)
    const float* dA = (const float*)d_in[1];   // (N, N)
    const float* dB = (const float*)d_in[2];   // (N,)
    float* out = (float*)d_out;                // (L, B, N)
    float* ws  = (float*)d_ws;

    bool mfma_ok = ws_size >= NEED_BYTES;      // ~35.7 MB

    k_transpose<<<256, 256, 0, stream>>>(dA, ws);
    k_qmm<<<1 * 32, 256, 0, stream>>>(ws, 1);    // power 2
    k_qmm<<<2 * 32, 256, 0, stream>>>(ws, 2);    // 3,4
    k_qmm<<<4 * 32, 256, 0, stream>>>(ws, 4);    // 5..8
    k_qmm<<<8 * 32, 256, 0, stream>>>(ws, 8);    // 9..16
    k_qmm<<<16 * 32, 256, 0, stream>>>(ws, 16);  // 17..32
    k_kvec<<<CC, 256, 0, stream>>>(dB, ws);

    unsigned short* qbh = (unsigned short*)(ws + F32_FLOATS);
    unsigned short* qbl = qbh + QB_ELEMS;
    unsigned short* sbh = qbl + QB_ELEMS;
    unsigned short* sbl = sbh + SB_ELEMS;

    if (mfma_ok)
        k_qsplit<<<(CC * KT * 16 * 64) / 256, 256, 0, stream>>>(ws, qbh, qbl);

    k_phase1<<<MM * 4, 256, 0, stream>>>(in, ws);
    k_phase2<<<BB, 1024, 0, stream>>>(ws);

    if (mfma_ok) {
        k_ssplit<<<(MM * KT * 8 * 64) / 256, 256, 0, stream>>>(in, ws, sbh, sbl);
        k_phase3_mfma<<<MM * CC * 2, 256, 0, stream>>>(sbh, sbl, qbh, qbl, out);
    } else {
        k_phase3<<<MM * CC * 4, 256, 0, stream>>>(in, out, ws);
    }
}